// Round 1
// baseline (432.427 us; speedup 1.0000x reference)
//
#include <hip/hip_runtime.h>

#define T_SEQ 2048
#define N_B   4
#define N_H   16
#define D_H   64
#define EMB   1024
#define LPAD  72   // padded LDS row stride (elements) — breaks power-of-2 bank stride

typedef __attribute__((ext_vector_type(8))) short vshort8;  // 8 bf16 (4 VGPRs)
typedef __attribute__((ext_vector_type(4))) float vfloat4;  // MFMA C/D

__device__ __forceinline__ ushort f2bf(float f) {
  union { float f; unsigned u; } v; v.f = f;
  unsigned u = v.u;
  return (ushort)((u + 0x7fffu + ((u >> 16) & 1u)) >> 16);  // RNE
}
__device__ __forceinline__ float bf2f(ushort b) {
  union { unsigned u; float f; } v; v.u = ((unsigned)b) << 16;
  return v.f;
}
__device__ __forceinline__ float fexp2(float x) {
#if __has_builtin(__builtin_amdgcn_exp2f)
  return __builtin_amdgcn_exp2f(x);
#else
  return exp2f(x);
#endif
}

// ---------------- QKV projection ----------------
// Q/K/V[bh][t][d] (bf16) = x[b][t][h*64+d] @ W^T via 16x16x32 bf16 MFMA.
// One wave per (16-row strip of B*T, head). A-frag: m=lane&15 (row), k=quad*8+j.
// B-frag: B[k][n] = W[n][k] -> load W row-major like an A operand (verified layout).
__global__ __launch_bounds__(256) void proj_qkv(
    const float* __restrict__ x, const float* __restrict__ Wq,
    const float* __restrict__ Wk, const float* __restrict__ Wv,
    ushort* __restrict__ Qw, ushort* __restrict__ Kw, ushort* __restrict__ Vw) {
  const int wid  = threadIdx.x >> 6;
  const int lane = threadIdx.x & 63;
  const int l15  = lane & 15;
  const int quad = lane >> 4;
  const int gw    = blockIdx.x * 4 + wid;   // 0..8191 wave tasks
  const int strip = gw >> 4;                // 16-row strip over B*T
  const int h     = gw & 15;
  const int r0    = strip * 16;
  const int b     = r0 >> 11;               // / 2048
  const int t0    = r0 & (T_SEQ - 1);
  const int bh    = b * N_H + h;

  vshort8 afr[2];
  {
    const float* xp = x + (size_t)(r0 + l15) * EMB + h * D_H + quad * 8;
#pragma unroll
    for (int kc = 0; kc < 2; ++kc) {
      float4 a0 = *(const float4*)(xp + kc * 32);
      float4 a1 = *(const float4*)(xp + kc * 32 + 4);
      vshort8 t;
      t[0] = (short)f2bf(a0.x); t[1] = (short)f2bf(a0.y);
      t[2] = (short)f2bf(a0.z); t[3] = (short)f2bf(a0.w);
      t[4] = (short)f2bf(a1.x); t[5] = (short)f2bf(a1.y);
      t[6] = (short)f2bf(a1.z); t[7] = (short)f2bf(a1.w);
      afr[kc] = t;
    }
  }

  const float* Ws[3] = {Wq, Wk, Wv};
  ushort*      Os[3] = {Qw, Kw, Vw};
#pragma unroll
  for (int m = 0; m < 3; ++m) {
    const float* W = Ws[m];
    vfloat4 acc[4];
#pragma unroll
    for (int nt = 0; nt < 4; ++nt) acc[nt] = (vfloat4){0.f, 0.f, 0.f, 0.f};
#pragma unroll
    for (int kc = 0; kc < 2; ++kc) {
#pragma unroll
      for (int nt = 0; nt < 4; ++nt) {
        const float* wp = W + (nt * 16 + l15) * D_H + kc * 32 + quad * 8;
        float4 w0 = *(const float4*)(wp);
        float4 w1 = *(const float4*)(wp + 4);
        vshort8 bfr;
        bfr[0] = (short)f2bf(w0.x); bfr[1] = (short)f2bf(w0.y);
        bfr[2] = (short)f2bf(w0.z); bfr[3] = (short)f2bf(w0.w);
        bfr[4] = (short)f2bf(w1.x); bfr[5] = (short)f2bf(w1.y);
        bfr[6] = (short)f2bf(w1.z); bfr[7] = (short)f2bf(w1.w);
        acc[nt] = __builtin_amdgcn_mfma_f32_16x16x32_bf16(afr[kc], bfr, acc[nt], 0, 0, 0);
      }
    }
    // C/D layout: col = lane&15, row = quad*4 + reg (verified m89/m91)
    ushort* op = Os[m] + ((size_t)bh * T_SEQ + t0) * D_H;
#pragma unroll
    for (int nt = 0; nt < 4; ++nt)
#pragma unroll
      for (int r = 0; r < 4; ++r)
        op[(quad * 4 + r) * D_H + nt * 16 + l15] = f2bf(acc[nt][r]);
  }
}

// ---------------- fused flash attention + V residual ----------------
// Block: one (bh), 64 query rows (4 waves x 16 rows). Loop over K-tiles of 64.
__global__ __launch_bounds__(256) void attn_fused(
    const ushort* __restrict__ Qw, const ushort* __restrict__ Kw,
    const ushort* __restrict__ Vw, float* __restrict__ out) {
  __shared__ ushort Kt[64 * LPAD];      // Kt[s][d]
  __shared__ ushort Vt[64 * LPAD];      // Vt[d][s]  (transposed for PV B-frags)
  __shared__ ushort Pa[4][16 * LPAD];   // per-wave P, A-operand staging

  const int tid  = threadIdx.x;
  const int wid  = tid >> 6;
  const int lane = tid & 63;
  const int l15  = lane & 15;
  const int quad = lane >> 4;
  const int bh   = blockIdx.y;
  const int t0   = blockIdx.x * 64;
  const int tw   = t0 + wid * 16;       // this wave's 16 query rows

  const size_t headoff = (size_t)bh * T_SEQ * D_H;

  // Q fragments (A layout: m = l15, k = quad*8+j), held for whole kernel
  vshort8 qf[2];
  {
    const ushort* qp = Qw + headoff + (size_t)(tw + l15) * D_H + quad * 8;
    qf[0] = *(const vshort8*)(qp);
    qf[1] = *(const vshort8*)(qp + 32);
  }

  vfloat4 oacc[4];
  float m_i[4], l_i[4];
#pragma unroll
  for (int nt = 0; nt < 4; ++nt) oacc[nt] = (vfloat4){0.f, 0.f, 0.f, 0.f};
#pragma unroll
  for (int r = 0; r < 4; ++r) { m_i[r] = -3.0e38f; l_i[r] = 0.f; }

  const float csc = 0.18033688011f;  // log2(e) / sqrt(64)

  for (int s0 = 0; s0 < T_SEQ; s0 += 64) {
    __syncthreads();  // previous iter's LDS reads done before restage
    // ---- stage K (row-major) and V (transposed) tiles ----
#pragma unroll
    for (int i = 0; i < 2; ++i) {
      const int c  = tid + i * 256;       // 512 chunks of 8 elements
      const int sl = c >> 3;
      const int dc = (c & 7) * 8;
      const size_t goff = headoff + (size_t)(s0 + sl) * D_H + dc;
      uint4 kv = *(const uint4*)(Kw + goff);
      *(uint4*)(&Kt[sl * LPAD + dc]) = kv;
      union { uint4 v; ushort s[8]; } vv;
      vv.v = *(const uint4*)(Vw + goff);
      // rotate store order by (c&7) so simultaneous lanes hit different banks
#pragma unroll
      for (int j = 0; j < 8; ++j) {
        const int jj = (j + (c & 7)) & 7;
        Vt[(dc + jj) * LPAD + sl] = vv.s[jj];
      }
    }
    __syncthreads();

    // ---- S = Q @ K^T  (B[k][n] = K[s0+nt*16+n][k] -> A-style load of Kt) ----
    vfloat4 sacc[4];
#pragma unroll
    for (int nt = 0; nt < 4; ++nt) sacc[nt] = (vfloat4){0.f, 0.f, 0.f, 0.f};
#pragma unroll
    for (int kc = 0; kc < 2; ++kc) {
#pragma unroll
      for (int nt = 0; nt < 4; ++nt) {
        vshort8 kf = *(const vshort8*)(&Kt[(nt * 16 + l15) * LPAD + kc * 32 + quad * 8]);
        sacc[nt] = __builtin_amdgcn_mfma_f32_16x16x32_bf16(qf[kc], kf, sacc[nt], 0, 0, 0);
      }
    }

    // ---- online softmax (rows quad*4+r live across the quad's 16 lanes) ----
    float sv[4][4];
#pragma unroll
    for (int nt = 0; nt < 4; ++nt)
#pragma unroll
      for (int r = 0; r < 4; ++r) sv[nt][r] = sacc[nt][r] * csc;

    float tm[4];
#pragma unroll
    for (int r = 0; r < 4; ++r)
      tm[r] = fmaxf(fmaxf(sv[0][r], sv[1][r]), fmaxf(sv[2][r], sv[3][r]));
#pragma unroll
    for (int off = 1; off < 16; off <<= 1)
#pragma unroll
      for (int r = 0; r < 4; ++r) tm[r] = fmaxf(tm[r], __shfl_xor(tm[r], off, 64));

    float alpha[4], psum[4];
#pragma unroll
    for (int r = 0; r < 4; ++r) {
      const float mn = fmaxf(m_i[r], tm[r]);
      alpha[r] = fexp2(m_i[r] - mn);
      m_i[r] = mn;
      psum[r] = 0.f;
    }
    float pv[4][4];
#pragma unroll
    for (int nt = 0; nt < 4; ++nt)
#pragma unroll
      for (int r = 0; r < 4; ++r) {
        const float p = fexp2(sv[nt][r] - m_i[r]);
        pv[nt][r] = p;
        psum[r] += p;
      }
#pragma unroll
    for (int off = 1; off < 16; off <<= 1)
#pragma unroll
      for (int r = 0; r < 4; ++r) psum[r] += __shfl_xor(psum[r], off, 64);
#pragma unroll
    for (int r = 0; r < 4; ++r) l_i[r] = l_i[r] * alpha[r] + psum[r];

#pragma unroll
    for (int nt = 0; nt < 4; ++nt)
#pragma unroll
      for (int r = 0; r < 4; ++r) oacc[nt][r] *= alpha[r];

    // ---- P: C-layout -> A-layout via per-wave LDS round trip ----
#pragma unroll
    for (int nt = 0; nt < 4; ++nt)
#pragma unroll
      for (int r = 0; r < 4; ++r)
        Pa[wid][(quad * 4 + r) * LPAD + nt * 16 + l15] = f2bf(pv[nt][r]);
    // same-wave producer/consumer: compiler inserts lgkmcnt waits

    // ---- O += P @ V  (B[k][n] = V[s=k][d=n] = Vt[n][k] -> b128 reads) ----
#pragma unroll
    for (int kc2 = 0; kc2 < 2; ++kc2) {
      vshort8 pf = *(const vshort8*)(&Pa[wid][l15 * LPAD + kc2 * 32 + quad * 8]);
#pragma unroll
      for (int nt = 0; nt < 4; ++nt) {
        vshort8 vf = *(const vshort8*)(&Vt[(nt * 16 + l15) * LPAD + kc2 * 32 + quad * 8]);
        oacc[nt] = __builtin_amdgcn_mfma_f32_16x16x32_bf16(pf, vf, oacc[nt], 0, 0, 0);
      }
    }
  }

  // ---- epilogue: O/l + V residual, fp32 out[b][t][h*64+d] ----
  const int b = bh >> 4;
  const int h = bh & 15;
#pragma unroll
  for (int r = 0; r < 4; ++r) {
    const int t = tw + quad * 4 + r;
    const float inv = 1.0f / l_i[r];
    const ushort* vresp = Vw + headoff + (size_t)t * D_H;
    float* op = out + ((size_t)(b * T_SEQ + t)) * EMB + h * D_H;
#pragma unroll
    for (int nt = 0; nt < 4; ++nt) {
      const int dcol = nt * 16 + l15;
      op[dcol] = oacc[nt][r] * inv + bf2f(vresp[dcol]);
    }
  }
}

extern "C" void kernel_launch(void* const* d_in, const int* in_sizes, int n_in,
                              void* d_out, int out_size, void* d_ws, size_t ws_size,
                              hipStream_t stream) {
  const float* x  = (const float*)d_in[0];
  const float* Wq = (const float*)d_in[1];
  const float* Wk = (const float*)d_in[2];
  const float* Wv = (const float*)d_in[3];
  float* out = (float*)d_out;

  const size_t per = (size_t)N_B * N_H * T_SEQ * D_H;  // 8,388,608 elements
  ushort* Qw = (ushort*)d_ws;
  ushort* Kw = Qw + per;
  ushort* Vw = Kw + per;
  // ws needed: 3 * per * 2 B = 50.3 MB

  // 8192 wave-tasks (512 row-strips x 16 heads) / 4 waves per block
  proj_qkv<<<2048, 256, 0, stream>>>(x, Wq, Wk, Wv, Qw, Kw, Vw);
  // grid: 32 q-tiles x 64 (b,h)
  attn_fused<<<dim3(32, 64), 256, 0, stream>>>(Qw, Kw, Vw, out);
}

// Round 2
// 260.316 us; speedup vs baseline: 1.6612x; 1.6612x over previous
//
#include <hip/hip_runtime.h>

#define T_SEQ 2048
#define N_B   4
#define N_H   16
#define D_H   64
#define EMB   1024
#define LPAD  72   // LDS row stride (elements); 144 B keeps b128 16B-aligned

typedef __attribute__((ext_vector_type(8))) short vshort8;  // 8 bf16 (4 VGPRs)
typedef __attribute__((ext_vector_type(4))) float vfloat4;  // MFMA C/D

__device__ __forceinline__ ushort f2bf(float f) {
  union { float f; unsigned u; } v; v.f = f;
  unsigned u = v.u;
  return (ushort)((u + 0x7fffu + ((u >> 16) & 1u)) >> 16);  // RNE
}
__device__ __forceinline__ unsigned pk2bf(float a, float b) {
  return (unsigned)f2bf(a) | ((unsigned)f2bf(b) << 16);
}
__device__ __forceinline__ float bf2f(ushort b) {
  union { unsigned u; float f; } v; v.u = ((unsigned)b) << 16;
  return v.f;
}
__device__ __forceinline__ float fexp2(float x) {
#if __has_builtin(__builtin_amdgcn_exp2f)
  return __builtin_amdgcn_exp2f(x);
#else
  return exp2f(x);
#endif
}

// ---------------- QKV projection ----------------
// Per wave: 16 rows of x (one head). Computes Q,K,V (row-major per head) AND
// V^T directly via operand-swapped MFMA: mfma(A=Wv_rows, B=x_frag) = V^T.
__global__ __launch_bounds__(256) void proj_qkv(
    const float* __restrict__ x, const float* __restrict__ Wq,
    const float* __restrict__ Wk, const float* __restrict__ Wv,
    ushort* __restrict__ Qw, ushort* __restrict__ Kw, ushort* __restrict__ Vw,
    ushort* __restrict__ Vtg) {
  const int wid  = threadIdx.x >> 6;
  const int lane = threadIdx.x & 63;
  const int l15  = lane & 15;
  const int quad = lane >> 4;
  const int gw    = blockIdx.x * 4 + wid;
  const int strip = gw >> 4;
  const int h     = gw & 15;
  const int r0    = strip * 16;
  const int b     = r0 >> 11;
  const int t0    = r0 & (T_SEQ - 1);
  const int bh    = b * N_H + h;

  // A-frag of x rows (also reused as the B-operand for the V^T MFMA):
  // lane holds x[t=r0+l15][h*64 + kc*32 + quad*8 + j]
  vshort8 afr[2];
  {
    const float* xp = x + (size_t)(r0 + l15) * EMB + h * D_H + quad * 8;
#pragma unroll
    for (int kc = 0; kc < 2; ++kc) {
      float4 a0 = *(const float4*)(xp + kc * 32);
      float4 a1 = *(const float4*)(xp + kc * 32 + 4);
      vshort8 t;
      t[0] = (short)f2bf(a0.x); t[1] = (short)f2bf(a0.y);
      t[2] = (short)f2bf(a0.z); t[3] = (short)f2bf(a0.w);
      t[4] = (short)f2bf(a1.x); t[5] = (short)f2bf(a1.y);
      t[6] = (short)f2bf(a1.z); t[7] = (short)f2bf(a1.w);
      afr[kc] = t;
    }
  }

  const float* Ws[3] = {Wq, Wk, Wv};
  ushort*      Os[3] = {Qw, Kw, Vw};
  const size_t headoff = (size_t)bh * T_SEQ * D_H;

#pragma unroll
  for (int m = 0; m < 3; ++m) {
    const float* W = Ws[m];
    vfloat4 acc[4], vtacc[4];
#pragma unroll
    for (int nt = 0; nt < 4; ++nt) {
      acc[nt]   = (vfloat4){0.f, 0.f, 0.f, 0.f};
      vtacc[nt] = (vfloat4){0.f, 0.f, 0.f, 0.f};
    }
#pragma unroll
    for (int kc = 0; kc < 2; ++kc) {
#pragma unroll
      for (int nt = 0; nt < 4; ++nt) {
        const float* wp = W + (nt * 16 + l15) * D_H + kc * 32 + quad * 8;
        float4 w0 = *(const float4*)(wp);
        float4 w1 = *(const float4*)(wp + 4);
        vshort8 wf;
        wf[0] = (short)f2bf(w0.x); wf[1] = (short)f2bf(w0.y);
        wf[2] = (short)f2bf(w0.z); wf[3] = (short)f2bf(w0.w);
        wf[4] = (short)f2bf(w1.x); wf[5] = (short)f2bf(w1.y);
        wf[6] = (short)f2bf(w1.z); wf[7] = (short)f2bf(w1.w);
        acc[nt] = __builtin_amdgcn_mfma_f32_16x16x32_bf16(afr[kc], wf, acc[nt], 0, 0, 0);
        if (m == 2)  // V^T = Wv * x^T : A=Wv rows, B=x frag
          vtacc[nt] = __builtin_amdgcn_mfma_f32_16x16x32_bf16(wf, afr[kc], vtacc[nt], 0, 0, 0);
      }
    }
    // normal store: C-layout col=l15 (d), row=quad*4+r (t)
    ushort* op = Os[m] + headoff + (size_t)t0 * D_H;
#pragma unroll
    for (int nt = 0; nt < 4; ++nt)
#pragma unroll
      for (int r = 0; r < 4; ++r)
        op[(quad * 4 + r) * D_H + nt * 16 + l15] = f2bf(acc[nt][r]);
    if (m == 2) {
      // V^T store: C-layout col=l15 (t), row=quad*4+r (d within 16nt)
      ushort* vp = Vtg + headoff;  // [d][t] per head
#pragma unroll
      for (int nt = 0; nt < 4; ++nt)
#pragma unroll
        for (int r = 0; r < 4; ++r)
          vp[(size_t)(nt * 16 + quad * 4 + r) * T_SEQ + t0 + l15] = f2bf(vtacc[nt][r]);
    }
  }
}

// ---------------- fused flash attention + V residual ----------------
// Block: one (bh), 128 query rows = 4 waves x 2 strips x 16 rows.
// Computes S^T = K·Q^T (softmax per-lane), then O = P·V with P from a packed
// b64 LDS round-trip. K tile + V^T tile staged by straight coalesced copies.
__global__ __launch_bounds__(256, 4) void attn_fused(
    const ushort* __restrict__ Qw, const ushort* __restrict__ Kw,
    const ushort* __restrict__ Vw, const ushort* __restrict__ Vtg,
    float* __restrict__ out) {
  __shared__ ushort Kt[64 * LPAD];        // K[s][d]
  __shared__ ushort Vt[64 * LPAD];        // V^T[d][s]
  __shared__ ushort Pa[4][2][16 * LPAD];  // per wave/strip: P[t][s] (row-major)

  const int tid  = threadIdx.x;
  const int wid  = tid >> 6;
  const int lane = tid & 63;
  const int l15  = lane & 15;
  const int quad = lane >> 4;
  const int bh   = blockIdx.y;
  const int t_base = blockIdx.x * 128;
  const int tws[2] = {t_base + wid * 16, t_base + 64 + wid * 16};

  const size_t headoff = (size_t)bh * T_SEQ * D_H;

  // Q fragments as the B-operand of S^T: lane holds Q[t=l15][d=kc*32+quad*8+j]
  vshort8 qf[2][2];
#pragma unroll
  for (int st = 0; st < 2; ++st) {
    const ushort* qp = Qw + headoff + (size_t)(tws[st] + l15) * D_H + quad * 8;
    qf[st][0] = *(const vshort8*)(qp);
    qf[st][1] = *(const vshort8*)(qp + 32);
  }

  vfloat4 oacc[2][4];
  float m_i[2], l_i[2];
#pragma unroll
  for (int st = 0; st < 2; ++st) {
#pragma unroll
    for (int nt = 0; nt < 4; ++nt) oacc[st][nt] = (vfloat4){0.f, 0.f, 0.f, 0.f};
    m_i[st] = -3.0e38f; l_i[st] = 0.f;
  }

  const float csc = 0.18033688011f;  // log2(e) / sqrt(64)

  for (int s0 = 0; s0 < T_SEQ; s0 += 64) {
    __syncthreads();
#pragma unroll
    for (int i = 0; i < 2; ++i) {
      const int c  = tid + i * 256;
      const int rr = c >> 3;           // K: s-row    | Vt: d-row
      const int cc = (c & 7) * 8;      // K: d-col    | Vt: s-col
      *(uint4*)(&Kt[rr * LPAD + cc]) =
          *(const uint4*)(Kw + headoff + (size_t)(s0 + rr) * D_H + cc);
      *(uint4*)(&Vt[rr * LPAD + cc]) =
          *(const uint4*)(Vtg + headoff + (size_t)rr * T_SEQ + s0 + cc);
    }
    __syncthreads();

    // ---- S^T = K·Q^T : A = K rows (m=s), B = Q frag (n=t) ----
    vfloat4 sacc[2][4];
#pragma unroll
    for (int st = 0; st < 2; ++st)
#pragma unroll
      for (int nt = 0; nt < 4; ++nt) sacc[st][nt] = (vfloat4){0.f, 0.f, 0.f, 0.f};
#pragma unroll
    for (int kc = 0; kc < 2; ++kc) {
#pragma unroll
      for (int nt = 0; nt < 4; ++nt) {
        vshort8 kf = *(const vshort8*)(&Kt[(nt * 16 + l15) * LPAD + kc * 32 + quad * 8]);
        sacc[0][nt] = __builtin_amdgcn_mfma_f32_16x16x32_bf16(kf, qf[0][kc], sacc[0][nt], 0, 0, 0);
        sacc[1][nt] = __builtin_amdgcn_mfma_f32_16x16x32_bf16(kf, qf[1][kc], sacc[1][nt], 0, 0, 0);
      }
    }

    // ---- softmax: column t = l15 lives in-lane (16 s-values) + quads ----
#pragma unroll
    for (int st = 0; st < 2; ++st) {
      float sv[4][4];
#pragma unroll
      for (int nt = 0; nt < 4; ++nt)
#pragma unroll
        for (int r = 0; r < 4; ++r) sv[nt][r] = sacc[st][nt][r] * csc;
      float tm = -3.0e38f;
#pragma unroll
      for (int nt = 0; nt < 4; ++nt)
#pragma unroll
        for (int r = 0; r < 4; ++r) tm = fmaxf(tm, sv[nt][r]);
      tm = fmaxf(tm, __shfl_xor(tm, 16, 64));
      tm = fmaxf(tm, __shfl_xor(tm, 32, 64));
      const float mn = fmaxf(m_i[st], tm);
      const float alpha = fexp2(m_i[st] - mn);
      m_i[st] = mn;
      float p[4][4];
      float ps = 0.f;
#pragma unroll
      for (int nt = 0; nt < 4; ++nt)
#pragma unroll
        for (int r = 0; r < 4; ++r) {
          p[nt][r] = fexp2(sv[nt][r] - mn);
          ps += p[nt][r];
        }
      ps += __shfl_xor(ps, 16, 64);
      ps += __shfl_xor(ps, 32, 64);
      l_i[st] = l_i[st] * alpha + ps;

      float aT[4];
#pragma unroll
      for (int r = 0; r < 4; ++r) aT[r] = __shfl(alpha, quad * 4 + r, 64);
#pragma unroll
      for (int nt = 0; nt < 4; ++nt)
#pragma unroll
        for (int r = 0; r < 4; ++r) oacc[st][nt][r] *= aT[r];

      // P[t=l15][s=16nt+4quad+r] -> packed b64 rows (A-layout staging)
#pragma unroll
      for (int nt = 0; nt < 4; ++nt) {
        uint2 w;
        w.x = pk2bf(p[nt][0], p[nt][1]);
        w.y = pk2bf(p[nt][2], p[nt][3]);
        *(uint2*)(&Pa[wid][st][l15 * LPAD + nt * 16 + quad * 4]) = w;
      }
    }

    // ---- O += P·V : A = P rows (m=t), B = V^T rows (n=d) ----
#pragma unroll
    for (int kc2 = 0; kc2 < 2; ++kc2) {
      vshort8 pf0 = *(const vshort8*)(&Pa[wid][0][l15 * LPAD + kc2 * 32 + quad * 8]);
      vshort8 pf1 = *(const vshort8*)(&Pa[wid][1][l15 * LPAD + kc2 * 32 + quad * 8]);
#pragma unroll
      for (int nt = 0; nt < 4; ++nt) {
        vshort8 vf = *(const vshort8*)(&Vt[(nt * 16 + l15) * LPAD + kc2 * 32 + quad * 8]);
        oacc[0][nt] = __builtin_amdgcn_mfma_f32_16x16x32_bf16(pf0, vf, oacc[0][nt], 0, 0, 0);
        oacc[1][nt] = __builtin_amdgcn_mfma_f32_16x16x32_bf16(pf1, vf, oacc[1][nt], 0, 0, 0);
      }
    }
  }

  // ---- epilogue: O/l + V residual; C-layout row=t(4quad+r), col=d(16nt+l15)
  const int b = bh >> 4;
  const int h = bh & 15;
#pragma unroll
  for (int st = 0; st < 2; ++st) {
    const float inv = 1.0f / l_i[st];
    float iT[4];
#pragma unroll
    for (int r = 0; r < 4; ++r) iT[r] = __shfl(inv, quad * 4 + r, 64);
#pragma unroll
    for (int r = 0; r < 4; ++r) {
      const int t = tws[st] + quad * 4 + r;
      const ushort* vresp = Vw + headoff + (size_t)t * D_H;
      float* op = out + ((size_t)(b * T_SEQ + t)) * EMB + h * D_H;
#pragma unroll
      for (int nt = 0; nt < 4; ++nt) {
        const int d = nt * 16 + l15;
        op[d] = oacc[st][nt][r] * iT[r] + bf2f(vresp[d]);
      }
    }
  }
}

extern "C" void kernel_launch(void* const* d_in, const int* in_sizes, int n_in,
                              void* d_out, int out_size, void* d_ws, size_t ws_size,
                              hipStream_t stream) {
  const float* x  = (const float*)d_in[0];
  const float* Wq = (const float*)d_in[1];
  const float* Wk = (const float*)d_in[2];
  const float* Wv = (const float*)d_in[3];
  float* out = (float*)d_out;

  const size_t per = (size_t)N_B * N_H * T_SEQ * D_H;  // 8,388,608 elements
  ushort* Qw  = (ushort*)d_ws;
  ushort* Kw  = Qw + per;
  ushort* Vw  = Kw + per;
  ushort* Vtg = Vw + per;   // V^T per head: [bh][d][t]
  // ws needed: 4 * per * 2 B = 67.1 MB

  proj_qkv<<<2048, 256, 0, stream>>>(x, Wq, Wk, Wv, Qw, Kw, Vw, Vtg);
  // 16 q-tiles of 128 rows x 64 (b,h)
  attn_fused<<<dim3(16, 64), 256, 0, stream>>>(Qw, Kw, Vw, Vtg, out);
}

// Round 3
// 172.992 us; speedup vs baseline: 2.4997x; 1.5048x over previous
//
#include <hip/hip_runtime.h>

#define T_SEQ 2048
#define N_B   4
#define N_H   16
#define D_H   64
#define EMB   1024
#define CSC   0.18033688011f  // log2(e) / sqrt(64), folded into Q at projection

typedef __attribute__((ext_vector_type(8))) short vshort8;  // 8 bf16 (4 VGPRs)
typedef __attribute__((ext_vector_type(4))) float vfloat4;  // MFMA C/D

__device__ __forceinline__ ushort f2bf(float f) {
  union { float f; unsigned u; } v; v.f = f;
  unsigned u = v.u;
  return (ushort)((u + 0x7fffu + ((u >> 16) & 1u)) >> 16);  // RNE
}
__device__ __forceinline__ unsigned pk2bf(float a, float b) {  // [bf(a),bf(b)] in mem
  return (unsigned)f2bf(a) | ((unsigned)f2bf(b) << 16);
}
__device__ __forceinline__ float bf2f(ushort b) {
  union { unsigned u; float f; } v; v.u = ((unsigned)b) << 16;
  return v.f;
}
__device__ __forceinline__ float fexp2(float x) {
#if __has_builtin(__builtin_amdgcn_exp2f)
  return __builtin_amdgcn_exp2f(x);
#else
  return exp2f(x);
#endif
}
// pack hi16(lo),hi16(hi) -> [bf_trunc(lo), bf_trunc(hi)] in memory (1 v_perm)
__device__ __forceinline__ unsigned permhi(float hi, float lo) {
  union { float f; unsigned u; } a, b; a.f = hi; b.f = lo;
#if __has_builtin(__builtin_amdgcn_perm)
  return __builtin_amdgcn_perm(a.u, b.u, 0x07060302u);
#else
  return (a.u & 0xFFFF0000u) | (b.u >> 16);
#endif
}

// Blob layout (per matrix): uint2 blob[bh][strip(128)][nt(4)][l15(16)][quad(4)]
//   Q/K: uint2 = 4 consecutive d at fixed row t/s (from swapped-MFMA C-layout)
//   V  : uint2 = 4 consecutive s at fixed d      (from normal-MFMA C-layout)
// Writes: lane (l15,quad) -> offset l15*4+quad => 512 B contiguous per (strip,nt).
// Reads (attn): b128 at [strip][2kc+(quad>>1)][l15][2*(quad&1)] gives each lane
// exactly its MFMA A/B fragment (d or s = kc*32 + quad*8 + j). Fully coalesced.

// ---------------- QKV projection ----------------
// Wave = 64 rows (4 strips) of one head. W-frags serve both MFMA orientations.
__global__ __launch_bounds__(256, 2) void proj_qkv(
    const float* __restrict__ x, const float* __restrict__ Wq,
    const float* __restrict__ Wk, const float* __restrict__ Wv,
    uint2* __restrict__ Qb, uint2* __restrict__ Kb, uint2* __restrict__ Vb) {
  const int wid  = threadIdx.x >> 6;
  const int lane = threadIdx.x & 63;
  const int l15  = lane & 15;
  const int quad = lane >> 4;
  const int gw = blockIdx.x * 4 + wid;   // [0,2048)
  const int rg = gw >> 4;                // 64-row group over B*T
  const int h  = gw & 15;
  const int r0 = rg * 64;
  const int b  = r0 >> 11;
  const int bh = b * N_H + h;
  const int ts0 = (r0 & (T_SEQ - 1)) >> 4;  // first strip index within head

  // x fragments: afr[st][kc] : lane holds x[r0+st*16+l15][h*64 + kc*32 + quad*8 + j]
  vshort8 afr[4][2];
#pragma unroll
  for (int st = 0; st < 4; ++st) {
    const float* xp = x + (size_t)(r0 + st * 16 + l15) * EMB + h * D_H + quad * 8;
#pragma unroll
    for (int kc = 0; kc < 2; ++kc) {
      float4 a0 = *(const float4*)(xp + kc * 32);
      float4 a1 = *(const float4*)(xp + kc * 32 + 4);
      vshort8 t;
      t[0] = (short)f2bf(a0.x); t[1] = (short)f2bf(a0.y);
      t[2] = (short)f2bf(a0.z); t[3] = (short)f2bf(a0.w);
      t[4] = (short)f2bf(a1.x); t[5] = (short)f2bf(a1.y);
      t[6] = (short)f2bf(a1.z); t[7] = (short)f2bf(a1.w);
      afr[st][kc] = t;
    }
  }

  const float* Ws[3] = {Wq, Wk, Wv};
  uint2*       Bs[3] = {Qb, Kb, Vb};
#pragma unroll
  for (int m = 0; m < 3; ++m) {
    // W frag: lane holds W[16nt+l15][kc*32+quad*8+j] (A- and B-layouts coincide)
    vshort8 wf[2][4];
#pragma unroll
    for (int kc = 0; kc < 2; ++kc)
#pragma unroll
      for (int nt = 0; nt < 4; ++nt) {
        const float* wp = Ws[m] + (nt * 16 + l15) * D_H + kc * 32 + quad * 8;
        float4 w0 = *(const float4*)(wp);
        float4 w1 = *(const float4*)(wp + 4);
        vshort8 t;
        t[0] = (short)f2bf(w0.x); t[1] = (short)f2bf(w0.y);
        t[2] = (short)f2bf(w0.z); t[3] = (short)f2bf(w0.w);
        t[4] = (short)f2bf(w1.x); t[5] = (short)f2bf(w1.y);
        t[6] = (short)f2bf(w1.z); t[7] = (short)f2bf(w1.w);
        wf[kc][nt] = t;
      }
    vfloat4 acc[4][4];
#pragma unroll
    for (int st = 0; st < 4; ++st)
#pragma unroll
      for (int nt = 0; nt < 4; ++nt) acc[st][nt] = (vfloat4){0.f, 0.f, 0.f, 0.f};
#pragma unroll
    for (int st = 0; st < 4; ++st)
#pragma unroll
      for (int kc = 0; kc < 2; ++kc)
#pragma unroll
        for (int nt = 0; nt < 4; ++nt)
          acc[st][nt] = (m < 2)
            ? __builtin_amdgcn_mfma_f32_16x16x32_bf16(wf[kc][nt], afr[st][kc], acc[st][nt], 0, 0, 0)
            : __builtin_amdgcn_mfma_f32_16x16x32_bf16(afr[st][kc], wf[kc][nt], acc[st][nt], 0, 0, 0);
    // Q/K (swapped): lane holds (d = 16nt+4quad+r, row = l15)  -> pack along d
    // V  (normal) : lane holds (row = 4quad+r,   d = 16nt+l15) -> pack along row
    uint2* B = Bs[m];
#pragma unroll
    for (int st = 0; st < 4; ++st)
#pragma unroll
      for (int nt = 0; nt < 4; ++nt) {
        vfloat4 a = acc[st][nt];
        if (m == 0) { a[0] *= CSC; a[1] *= CSC; a[2] *= CSC; a[3] *= CSC; }
        uint2 w;
        w.x = pk2bf(a[0], a[1]);
        w.y = pk2bf(a[2], a[3]);
        B[(((size_t)bh * 128 + ts0 + st) * 4 + nt) * 64 + l15 * 4 + quad] = w;
      }
  }
}

// ---------------- fused flash attention (no-max softmax) + V residual --------
// Wave = 64 q-rows (4 strips), block = 4 waves (256 t) of one (b,h).
// No block-level LDS sharing, no __syncthreads. K/V frags direct from L2/L1.
__global__ __launch_bounds__(256, 2) void attn_fused(
    const uint2* __restrict__ Qb, const uint2* __restrict__ Kb,
    const uint2* __restrict__ Vb, float* __restrict__ out) {
  __shared__ ushort Pa[4 * 1024];  // per-wave 16x64 P tile, XOR-swizzled chunks

  const int tid  = threadIdx.x;
  const int wid  = tid >> 6;
  const int lane = tid & 63;
  const int l15  = lane & 15;
  const int quad = lane >> 4;
  const int qh   = quad >> 1;
  const int q1   = quad & 1;

  // XCD swizzle: 16 consecutive per-XCD slots share a bh -> K/V stay in that L2
  const int blk  = blockIdx.x;                 // [0,512)
  const int work = (blk & 7) * 64 + (blk >> 3);
  const int bh   = work >> 3;
  const int tblk = work & 7;
  const int b = bh >> 4, h = bh & 15;
  const int tstrip0 = tblk * 16 + wid * 4;     // first of this wave's 4 strips

  const size_t hb = (size_t)bh * 128;
  const int laneoff = l15 * 4 + 2 * q1;        // uint2 units

  // Q frags (B-operand of S^T): lane holds Q[t=l15][d=kc*32+quad*8+j] * CSC
  vshort8 qf[4][2];
#pragma unroll
  for (int st = 0; st < 4; ++st)
#pragma unroll
    for (int kc = 0; kc < 2; ++kc)
      qf[st][kc] = *(const vshort8*)(&Qb[((hb + tstrip0 + st) * 4 + 2 * kc + qh) * 64 + laneoff]);

  vfloat4 oacc[4][4];
  float lsum[4];
#pragma unroll
  for (int st = 0; st < 4; ++st) {
#pragma unroll
    for (int nt = 0; nt < 4; ++nt) oacc[st][nt] = (vfloat4){0.f, 0.f, 0.f, 0.f};
    lsum[st] = 0.f;
  }

  ushort* Paw = &Pa[wid * 1024];
  const int parow = l15 * 64;   // elements
  const int swz   = l15 & 7;

  for (int ss = 0; ss < 128; ss += 4) {  // 32 s-tiles of 64
    // K A-frags: lane holds K[s=16snt+l15][d=kc*32+quad*8+j]
    vshort8 kf[4][2];
#pragma unroll
    for (int snt = 0; snt < 4; ++snt)
#pragma unroll
      for (int kc = 0; kc < 2; ++kc)
        kf[snt][kc] = *(const vshort8*)(&Kb[((hb + ss + snt) * 4 + 2 * kc + qh) * 64 + laneoff]);
    // V^T B-frags: lane holds V[s=kc2*32+quad*8+j][d=16dnt+l15]
    vshort8 vf[2][4];
#pragma unroll
    for (int kc2 = 0; kc2 < 2; ++kc2)
#pragma unroll
      for (int dnt = 0; dnt < 4; ++dnt)
        vf[kc2][dnt] = *(const vshort8*)(&Vb[((hb + ss + 2 * kc2 + qh) * 4 + dnt) * 64 + laneoff]);

#pragma unroll
    for (int st = 0; st < 4; ++st) {
      // S^T = K * Q^T (csc pre-folded): C holds (s = 16nt+4quad+r, t = l15)
      vfloat4 sacc[4];
#pragma unroll
      for (int nt = 0; nt < 4; ++nt) sacc[nt] = (vfloat4){0.f, 0.f, 0.f, 0.f};
#pragma unroll
      for (int kc = 0; kc < 2; ++kc)
#pragma unroll
        for (int nt = 0; nt < 4; ++nt)
          sacc[nt] = __builtin_amdgcn_mfma_f32_16x16x32_bf16(kf[nt][kc], qf[st][kc], sacc[nt], 0, 0, 0);

      // no-max softmax: p = exp2(sacc); per-lane partial l; P -> Pa (swizzled)
      float ls = 0.f;
#pragma unroll
      for (int nt = 0; nt < 4; ++nt) {
        const float p0 = fexp2(sacc[nt][0]);
        const float p1 = fexp2(sacc[nt][1]);
        const float p2 = fexp2(sacc[nt][2]);
        const float p3 = fexp2(sacc[nt][3]);
        ls += (p0 + p1) + (p2 + p3);
        uint2 w;
        w.x = permhi(p1, p0);
        w.y = permhi(p3, p2);
        *(uint2*)(&Paw[parow + (((2 * nt + qh) ^ swz) << 3) + 4 * q1]) = w;
      }
      lsum[st] += ls;

      // O += P * V : A = P rows (m=t=l15-row), B = V^T frags
#pragma unroll
      for (int kc2 = 0; kc2 < 2; ++kc2) {
        vshort8 pf = *(const vshort8*)(&Paw[parow + (((4 * kc2 + quad) ^ swz) << 3)]);
#pragma unroll
        for (int dnt = 0; dnt < 4; ++dnt)
          oacc[st][dnt] = __builtin_amdgcn_mfma_f32_16x16x32_bf16(pf, vf[kc2][dnt], oacc[st][dnt], 0, 0, 0);
      }
    }
  }

  // epilogue: l-reduce across quads, O/l + V residual (V from Vb blob)
#pragma unroll
  for (int st = 0; st < 4; ++st) {
    float l = lsum[st];
    l += __shfl_xor(l, 16, 64);
    l += __shfl_xor(l, 32, 64);
    const float inv = 1.0f / l;            // valid at lane index l15 (= t)
    float iT[4];
#pragma unroll
    for (int r = 0; r < 4; ++r) iT[r] = __shfl(inv, quad * 4 + r, 64);
    const int tstrip = tstrip0 + st;
#pragma unroll
    for (int nt = 0; nt < 4; ++nt) {
      uint2 vr = Vb[((hb + tstrip) * 4 + nt) * 64 + l15 * 4 + quad];
      float vres[4];
      vres[0] = bf2f((ushort)(vr.x & 0xFFFFu));
      vres[1] = bf2f((ushort)(vr.x >> 16));
      vres[2] = bf2f((ushort)(vr.y & 0xFFFFu));
      vres[3] = bf2f((ushort)(vr.y >> 16));
#pragma unroll
      for (int r = 0; r < 4; ++r) {
        const int t = tstrip * 16 + quad * 4 + r;
        out[((size_t)(b * T_SEQ + t)) * EMB + h * D_H + nt * 16 + l15] =
            oacc[st][nt][r] * iT[r] + vres[r];
      }
    }
  }
}

extern "C" void kernel_launch(void* const* d_in, const int* in_sizes, int n_in,
                              void* d_out, int out_size, void* d_ws, size_t ws_size,
                              hipStream_t stream) {
  const float* x  = (const float*)d_in[0];
  const float* Wq = (const float*)d_in[1];
  const float* Wk = (const float*)d_in[2];
  const float* Wv = (const float*)d_in[3];
  float* out = (float*)d_out;

  const size_t per = (size_t)64 * 128 * 4 * 16 * 4;  // 2,097,152 uint2 per blob
  uint2* Qb = (uint2*)d_ws;
  uint2* Kb = Qb + per;
  uint2* Vb = Kb + per;
  // ws needed: 3 * per * 8 B = 50.3 MB

  proj_qkv<<<512, 256, 0, stream>>>(x, Wq, Wk, Wv, Qb, Kb, Vb);
  attn_fused<<<512, 256, 0, stream>>>(Qb, Kb, Vb, out);
}